// Round 6
// baseline (2619.860 us; speedup 1.0000x reference)
//
#include <hip/hip_runtime.h>

// Decoder, B=16, T=64, S=128, D_ENC=512, U=256, V=32000.
// Round 6: persistent recurrence, tree grid-barrier (8 leaves + root epoch),
// row-major coherent exchange buffer x[b][1024] for coalesced L3 traffic.
// Epilogue: one bf16 MFMA vocab GEMM + exp + rowsum, deferred softmax scale.

#define NB 16
#define NT 64
#define NS 128
#define DE 512
#define NU 256
#define NV 32000
#define NBLK 256

// ws layout (floats); total 18.32 MB (<= proven available from round 5)
static const size_t OFF_KEYS = 0;         // keysT bf16 [16][256][128] = 262144 fl
static const size_t OFF_XT   = 262144;    // x [16][1024] fp32 (0-511 ctx, 512-767 emb, 768-1023 h)
static const size_t OFF_BAR  = 278528;    // barrier: root + 8 leaf counters (576 ints, padded)
static const size_t OFF_ZP   = 286720;    // zp [4][16][1024]
static const size_t OFF_RS   = 352256;    // rowsums [1024]
static const size_t OFF_HBUF = 353296;    // Hb fragment-tiled bf16 = 131072 fl
static const size_t OFF_WDT  = 484368;    // wdT fragment-tiled bf16 = 4096000 fl

typedef __attribute__((ext_vector_type(8))) short bf16x8;
typedef __attribute__((ext_vector_type(4))) float f32x4;

__device__ __forceinline__ float bf2f(unsigned int us) { return __uint_as_float(us << 16); }
__device__ __forceinline__ unsigned short f2bf(float f) {
    unsigned int u = __float_as_uint(f);
    return (unsigned short)((u + 0x7fffu + ((u >> 16) & 1u)) >> 16);
}
__device__ __forceinline__ float rcp_fast(float x) { return __builtin_amdgcn_rcpf(x); }
__device__ __forceinline__ float sigm(float x) { return rcp_fast(1.0f + __expf(-x)); }
__device__ __forceinline__ float tanh1(float x) {
    float e = __expf(2.0f * x);
    return 1.0f - 2.0f * rcp_fast(e + 1.0f);
}

// coherent (L3-point) accesses for cross-phase data: bypass non-coherent L2
__device__ __forceinline__ void cstore(float* p, float v) {
    __hip_atomic_store(p, v, __ATOMIC_RELAXED, __HIP_MEMORY_SCOPE_AGENT);
}
__device__ __forceinline__ float cload(const float* p) {
    return __hip_atomic_load(p, __ATOMIC_RELAXED, __HIP_MEMORY_SCOPE_AGENT);
}

// tree barrier: 8 leaf counters (one per blk&7 group, 256B apart -> parallel
// TCC channels) + root epoch counter. Monotonic, no resets. Fence-free:
// __syncthreads drains each wave's vmcnt (coherent stores at L3 on arrival);
// waiters poll root with relaxed loads only.
__device__ __forceinline__ void gbar(int* bar, int epoch) {
    __syncthreads();
    if (threadIdx.x == 0) {
        asm volatile("s_waitcnt vmcnt(0) lgkmcnt(0)" ::: "memory");
        int g = blockIdx.x & 7;
        int* leaf = bar + 64 + g * 64;
        int old = __hip_atomic_fetch_add(leaf, 1, __ATOMIC_RELAXED, __HIP_MEMORY_SCOPE_AGENT);
        if (old == epoch * 32 - 1)
            __hip_atomic_fetch_add(bar, 1, __ATOMIC_RELAXED, __HIP_MEMORY_SCOPE_AGENT);
        while (__hip_atomic_load(bar, __ATOMIC_RELAXED, __HIP_MEMORY_SCOPE_AGENT) < epoch * 8) {
            __builtin_amdgcn_s_sleep(4);
        }
        asm volatile("" ::: "memory");
    }
    __syncthreads();
}

// ---------------- init: x h rows, rs, barrier counters ----------------
__launch_bounds__(256)
__global__ void init_kernel(const float* __restrict__ h0, float* __restrict__ xT,
                            float* __restrict__ rs, int* __restrict__ bar) {
    int b = blockIdx.x, u = threadIdx.x;
    xT[b * 1024 + 768 + u] = h0[b * NU + u];
    if (u < 64) rs[b * 64 + u] = 0.f;
    int idx = b * 256 + u;
    if (idx < 576) bar[idx] = 0;
}

// ---------------- keys^T = (enc @ W2 + b2)^T  -> keysT[b][u][s] bf16 ----------------
__launch_bounds__(256)
__global__ void keys_kernel(const float* __restrict__ enc, const float* __restrict__ W2,
                            const float* __restrict__ b2, unsigned short* __restrict__ keysT) {
    __shared__ float els[8 * DE];  // 16 KB
    int b = blockIdx.x >> 4, so = blockIdx.x & 15;
    int u = threadIdx.x;
    const float4* src = (const float4*)(enc + ((size_t)b * NS + so * 8) * DE);
    float4* dst = (float4*)els;
    for (int i = u; i < 8 * DE / 4; i += 256) dst[i] = src[i];
    __syncthreads();
    float bias = b2[u];
    float acc[8];
#pragma unroll
    for (int ss = 0; ss < 8; ss++) acc[ss] = bias;
#pragma unroll 4
    for (int d = 0; d < DE; d++) {
        float w = W2[d * NU + u];
#pragma unroll
        for (int ss = 0; ss < 8; ss++) acc[ss] = fmaf(els[ss * DE + d], w, acc[ss]);
    }
    unsigned int w0 = (unsigned int)f2bf(acc[0]) | ((unsigned int)f2bf(acc[1]) << 16);
    unsigned int w1 = (unsigned int)f2bf(acc[2]) | ((unsigned int)f2bf(acc[3]) << 16);
    unsigned int w2 = (unsigned int)f2bf(acc[4]) | ((unsigned int)f2bf(acc[5]) << 16);
    unsigned int w3 = (unsigned int)f2bf(acc[6]) | ((unsigned int)f2bf(acc[7]) << 16);
    *(uint4*)(keysT + ((size_t)b * NU + u) * NS + so * 8) = make_uint4(w0, w1, w2, w3);
}

// ---------------- Wd -> fragment-tiled bf16 ----------------
__launch_bounds__(256)
__global__ void wdtile_kernel(const float* __restrict__ Wd, unsigned short* __restrict__ wdT) {
    int id = blockIdx.x * 256 + threadIdx.x;  // 0 .. 1,023,999
    int l = id & 63, c16 = (id >> 6) & 7, ks = (id >> 9) & 7, p = id >> 12;
    int v = p * 128 + c16 * 16 + (l & 15);
    int k0 = ks * 32 + (l >> 4) * 8;
    unsigned int wout[4];
#pragma unroll
    for (int jj = 0; jj < 4; jj++) {
        unsigned int lo = f2bf(Wd[(size_t)(k0 + 2 * jj) * NV + v]);
        unsigned int hi = f2bf(Wd[(size_t)(k0 + 2 * jj + 1) * NV + v]);
        wout[jj] = lo | (hi << 16);
    }
    *(uint4*)(wdT + (size_t)id * 8) = make_uint4(wout[0], wout[1], wout[2], wout[3]);
}

// ---------------- persistent recurrence: 64 steps, 2 phases/step ----------------
__launch_bounds__(256, 1)
__global__ void recur_kernel(const int* __restrict__ dec, const float* __restrict__ enc,
                             const float* __restrict__ emb, const float* __restrict__ W1,
                             const float* __restrict__ b1, const float* __restrict__ Va,
                             const float* __restrict__ bV, const float* __restrict__ Wx,
                             const float* __restrict__ Wh, const float* __restrict__ b_lstm,
                             const float* __restrict__ h0, const float* __restrict__ c0,
                             const unsigned short* __restrict__ keysT, float* __restrict__ xT,
                             float* __restrict__ zp, unsigned short* __restrict__ Hb,
                             int* __restrict__ bar) {
    __shared__ float smem[4352];  // B: xs[256][17]; A: hl|qv|scp|red|attn
    int blk = blockIdx.x, tid = threadIdx.x;
    int nbar = 0;
    int ab = blk >> 2, aq = blk & 3;  // phase-A role: batch, quarter
    // LSTM cell state in registers (each (b,q) replica maintains its own copy)
    float c_reg = (blk < 64) ? c0[ab * NU + tid] : 0.f;

    for (int it = 0; it <= NT; ++it) {
        // ---------- phase A: gates (it>0) + attention (it<NT) on blocks 0..63 ----------
        if (blk < 64) {
            int b = ab, q = aq;
            float* hl = smem;
            float* qv = smem + 256;
            float* scp = smem + 512;
            float* red = smem + 768;
            float* attn = smem + 896;
            int u = tid;
            float hn;
            if (it > 0) {
                const float* zpb = zp + b * 1024 + u;
                float zg4[4];
#pragma unroll
                for (int g = 0; g < 4; g++) {
                    zg4[g] = b_lstm[g * 256 + u] + cload(zpb + 0 * 16384 + g * 256) +
                             cload(zpb + 1 * 16384 + g * 256) +
                             cload(zpb + 2 * 16384 + g * 256) +
                             cload(zpb + 3 * 16384 + g * 256);
                }
                float cn = sigm(zg4[1]) * c_reg + sigm(zg4[0]) * tanh1(zg4[2]);
                c_reg = cn;
                hn = sigm(zg4[3]) * tanh1(cn);
                if (q == 0) {
                    cstore(&xT[b * 1024 + 768 + u], hn);
                    int r = (it - 1) * NB + b;
                    int mp = r >> 7, lr = r & 127;
                    int chunk = ((u >> 5) * 8 + (lr >> 4)) * 64 + ((u >> 3) & 3) * 16 + (lr & 15);
                    Hb[(size_t)mp * 32768 + chunk * 8 + (u & 7)] = f2bf(hn);
                }
            } else {
                hn = h0[b * NU + u];
            }
            hl[u] = hn;
            __syncthreads();
            if (it < NT) {
                // q = h @ W1 + b1 (replicated across the 4 q-blocks)
                float a = b1[u];
#pragma unroll 4
                for (int d = 0; d < NU; d++) a = fmaf(hl[d], W1[d * NU + u], a);
                qv[u] = a;
                __syncthreads();
                // scores: thread = (s, u-half)
                int s = tid & 127, uh = tid >> 7;
                const unsigned short* kp = keysT + ((size_t)b * NU + uh * 128) * NS + s;
                float sc = 0.f;
#pragma unroll 4
                for (int uu = 0; uu < 128; uu++)
                    sc = fmaf(tanh1(qv[uh * 128 + uu] + bf2f(kp[(size_t)uu * NS])),
                              Va[uh * 128 + uu], sc);
                scp[uh * NS + s] = sc;
                __syncthreads();
                float scfull = 0.f, p = 0.f;
                if (tid < NS) {
                    scfull = scp[tid] + scp[NS + tid] + bV[0];
                    red[tid] = scfull;
                }
                __syncthreads();
                for (int off = 64; off >= 1; off >>= 1) {
                    if (tid < off) red[tid] = fmaxf(red[tid], red[tid + off]);
                    __syncthreads();
                }
                float m = red[0];
                __syncthreads();
                if (tid < NS) {
                    p = __expf(scfull - m);
                    red[tid] = p;
                }
                __syncthreads();
                for (int off = 64; off >= 1; off >>= 1) {
                    if (tid < off) red[tid] += red[tid + off];
                    __syncthreads();
                }
                float tot = red[0];
                if (tid < NS) attn[tid] = p / tot;
                __syncthreads();
                // ctx quarter: d = q*128 + (tid&127), s-half = tid>>7
                int dl = tid & 127, sh = tid >> 7;
                const float* ep = enc + ((size_t)b * NS + sh * 64) * DE + q * 128 + dl;
                float cp = 0.f;
#pragma unroll 4
                for (int i2 = 0; i2 < 64; i2++)
                    cp = fmaf(attn[sh * 64 + i2], ep[(size_t)i2 * DE], cp);
                scp[sh * 128 + dl] = cp;
                __syncthreads();
                // coalesced row-major writes: x[b][q*128 + k]
                if (tid < 128) cstore(&xT[b * 1024 + q * 128 + tid], scp[tid] + scp[128 + tid]);
                if (q == 3) {
                    int tok = dec[b * NT + it];
                    tok = (tok < 0) ? 0 : (tok >= NV ? NV - 1 : tok);
                    cstore(&xT[b * 1024 + 512 + u], emb[(size_t)tok * NU + u]);
                }
            }
        }
        gbar(bar, ++nbar);
        if (it == NT) break;

        // ---------- phase B: z partials, 256 blocks = 64 j-groups x 4 k-quarters ----------
        {
            int jg = blk >> 2, kq = blk & 3;
            float* xs = smem;  // [256][17], k-major
            // coalesced: lane tid reads k = kq*256+tid of row b
#pragma unroll
            for (int b = 0; b < 16; b++)
                xs[tid * 17 + b] = cload(xT + (size_t)b * 1024 + kq * 256 + tid);
            __syncthreads();
            int jl = tid & 15, b = tid >> 4;
            int j = jg * 16 + jl;
            const float* wp = (kq < 3) ? (Wx + (size_t)(kq * 256) * 1024 + j) : (Wh + j);
            float a0 = 0.f, a1 = 0.f, a2 = 0.f, a3 = 0.f;
#pragma unroll 4
            for (int i2 = 0; i2 < 256; i2 += 4) {
                a0 = fmaf(wp[(size_t)(i2 + 0) * 1024], xs[(i2 + 0) * 17 + b], a0);
                a1 = fmaf(wp[(size_t)(i2 + 1) * 1024], xs[(i2 + 1) * 17 + b], a1);
                a2 = fmaf(wp[(size_t)(i2 + 2) * 1024], xs[(i2 + 2) * 17 + b], a2);
                a3 = fmaf(wp[(size_t)(i2 + 3) * 1024], xs[(i2 + 3) * 17 + b], a3);
            }
            cstore(&zp[(kq * 16 + b) * 1024 + j], (a0 + a1) + (a2 + a3));
        }
        gbar(bar, ++nbar);
    }
}

// ---------------- batched vocab GEMM + exp + rowsum ----------------
__launch_bounds__(256)
__global__ void gemm_kernel(const unsigned short* __restrict__ Hb,
                            const unsigned short* __restrict__ wdT,
                            const float* __restrict__ bd, float* __restrict__ out,
                            float* __restrict__ rs) {
    int w = (blockIdx.x & 7) * 250 + (blockIdx.x >> 3);
    int np = w >> 3, mp = w & 7;
    int wave = threadIdx.x >> 6, l = threadIdx.x & 63;
    int wm = wave >> 1, wn = wave & 1;
    const bf16x8* A = (const bf16x8*)Hb + (size_t)mp * 4096;
    const bf16x8* B = (const bf16x8*)wdT + (size_t)np * 4096;
    f32x4 acc[4][4];
#pragma unroll
    for (int mf = 0; mf < 4; mf++)
#pragma unroll
        for (int nf = 0; nf < 4; nf++) acc[mf][nf] = (f32x4){0.f, 0.f, 0.f, 0.f};
#pragma unroll
    for (int ks = 0; ks < 8; ks++) {
        bf16x8 av[4], bv[4];
#pragma unroll
        for (int mf = 0; mf < 4; mf++) av[mf] = A[(ks * 8 + wm * 4 + mf) * 64 + l];
#pragma unroll
        for (int nf = 0; nf < 4; nf++) bv[nf] = B[(ks * 8 + wn * 4 + nf) * 64 + l];
#pragma unroll
        for (int mf = 0; mf < 4; mf++)
#pragma unroll
            for (int nf = 0; nf < 4; nf++)
                acc[mf][nf] =
                    __builtin_amdgcn_mfma_f32_16x16x32_bf16(av[mf], bv[nf], acc[mf][nf], 0, 0, 0);
    }
    int colg = np * 128 + wn * 64;
    int rowg = mp * 128 + wm * 64;
#pragma unroll
    for (int mf = 0; mf < 4; mf++) {
        float rloc[4] = {0.f, 0.f, 0.f, 0.f};
#pragma unroll
        for (int nf = 0; nf < 4; nf++) {
            int col = colg + nf * 16 + (l & 15);
            float bdv = bd[col];
#pragma unroll
            for (int reg = 0; reg < 4; reg++) {
                int r = rowg + mf * 16 + (l >> 4) * 4 + reg;  // r = t*16 + b
                float p = __expf(acc[mf][nf][reg] + bdv);
                out[(size_t)((r & 15) * NT + (r >> 4)) * NV + col] = p;
                rloc[reg] += p;
            }
        }
#pragma unroll
        for (int reg = 0; reg < 4; reg++) {
            float v = rloc[reg];
            v += __shfl_xor(v, 1);
            v += __shfl_xor(v, 2);
            v += __shfl_xor(v, 4);
            v += __shfl_xor(v, 8);
            if ((l & 15) == 0) atomicAdd(&rs[rowg + mf * 16 + (l >> 4) * 4 + reg], v);
        }
    }
}

// ---------------- final softmax normalization ----------------
__launch_bounds__(256)
__global__ void scale_kernel(float* __restrict__ out, const float* __restrict__ rs) {
    int o = blockIdx.x;  // out row = b*64 + t
    int b = o >> 6, t = o & 63;
    float rinv = 1.0f / rs[t * NB + b];
    float4* op = (float4*)(out + (size_t)o * NV);
    for (int i = threadIdx.x; i < NV / 4; i += 256) {
        float4 v = op[i];
        v.x *= rinv; v.y *= rinv; v.z *= rinv; v.w *= rinv;
        op[i] = v;
    }
}

extern "C" void kernel_launch(void* const* d_in, const int* in_sizes, int n_in,
                              void* d_out, int out_size, void* d_ws, size_t ws_size,
                              hipStream_t stream) {
    const int* dec = (const int*)d_in[0];
    const float* enc = (const float*)d_in[1];
    const float* h0 = (const float*)d_in[2];
    const float* c0 = (const float*)d_in[3];
    const float* emb = (const float*)d_in[4];
    const float* W1 = (const float*)d_in[5];
    const float* b1 = (const float*)d_in[6];
    const float* W2 = (const float*)d_in[7];
    const float* b2 = (const float*)d_in[8];
    const float* Va = (const float*)d_in[9];
    const float* bV = (const float*)d_in[10];
    const float* Wx = (const float*)d_in[11];
    const float* Wh = (const float*)d_in[12];
    const float* b_lstm = (const float*)d_in[13];
    const float* Wd = (const float*)d_in[14];
    const float* bd = (const float*)d_in[15];
    float* out = (float*)d_out;
    float* ws = (float*)d_ws;

    unsigned short* keysT = (unsigned short*)(ws + OFF_KEYS);
    float* xT = ws + OFF_XT;
    float* zp = ws + OFF_ZP;
    float* ws_rs = ws + OFF_RS;
    int* bar = (int*)(ws + OFF_BAR);
    unsigned short* Hb = (unsigned short*)(ws + OFF_HBUF);
    unsigned short* wdT = (unsigned short*)(ws + OFF_WDT);

    init_kernel<<<16, 256, 0, stream>>>(h0, xT, ws_rs, bar);
    keys_kernel<<<256, 256, 0, stream>>>(enc, W2, b2, keysT);
    wdtile_kernel<<<4000, 256, 0, stream>>>(Wd, wdT);
    recur_kernel<<<NBLK, 256, 0, stream>>>(dec, enc, emb, W1, b1, Va, bV, Wx, Wh, b_lstm,
                                           h0, c0, keysT, xT, zp, Hb, bar);
    gemm_kernel<<<2000, 256, 0, stream>>>(Hb, wdT, bd, out, ws_rs);
    scale_kernel<<<1024, 256, 0, stream>>>(out, ws_rs);
}